// Round 6
// baseline (420.928 us; speedup 1.0000x reference)
//
#include <hip/hip_runtime.h>
#include <hip/hip_bf16.h>

// Problem constants (ResNet-50 CBP head)
#define BATCH 8
#define CH    2048
#define LSP   784          // H*W = 28*28
#define KPAD  800          // pad K to 25*32 for MFMA k-steps
#define KSTEPS (KPAD/32)   // 25
#define DDIM  8192         // count-sketch dim (power of 2)
#define NCLS  200
#define NTILE 16           // 2048/128 tiles per dim
#define NPAIR 136          // NTILE*(NTILE+1)/2 symmetric tile pairs
#define NSLOT 17           // part slots per batch (136/17 = 8 blocks share a slot)

typedef __bf16 bf16x8 __attribute__((ext_vector_type(8)));
typedef float  f32x4  __attribute__((ext_vector_type(4)));

// Native FP atomics (ds_add_f32 / global_atomic_add_f32). Plain atomicAdd
// without -munsafe-fp-atomics expands to a CAS retry loop (two dependent
// ~120-250cyc round-trips per op) — measured as the ~186us scatter floor.
#define FATOMIC(p, v) unsafeAtomicAdd((p), (v))

// fp32 -> bf16 round-to-nearest-even (bit pattern)
__device__ __forceinline__ unsigned short f2bf_rn(float f) {
    unsigned int u = __float_as_uint(f);
    unsigned int r = u + 0x7fffu + ((u >> 16) & 1u);
    return (unsigned short)(r >> 16);
}

// ---------------------------------------------------------------------------
// Kernel 1: split x into hi/lo bf16 [B,C,KPAD] (vec4).  Also zero-inits the
// part array + norm accumulators and seeds logits with the bias.
// ---------------------------------------------------------------------------
__global__ __launch_bounds__(256) void split_kernel(
    const float* __restrict__ x,
    unsigned short* __restrict__ xhi,
    unsigned short* __restrict__ xlo,
    float* __restrict__ part, float* __restrict__ norm,
    const float* __restrict__ bc, float* __restrict__ out)
{
    int idx = blockIdx.x * 256 + threadIdx.x;          // vec4 index
    if (idx < NSLOT * BATCH * DDIM) part[idx] = 0.0f;
    if (idx < BATCH) norm[idx] = 0.0f;
    if (idx < BATCH * NCLS) out[idx] = bc[idx % NCLS]; // bias-seed logits
    if (idx >= BATCH * CH * KPAD / 4) return;
    int v  = idx * 4;
    int bc_ = v / KPAD;
    int l  = v - bc_ * KPAD;                           // multiple of 4
    float4 xv = make_float4(0.f, 0.f, 0.f, 0.f);
    if (l < LSP)                                       // LSP%4==0: uniform per vec
        xv = *(const float4*)&x[(size_t)bc_ * LSP + l];
    ushort4 hv, lv;
    float f[4] = {xv.x, xv.y, xv.z, xv.w};
    unsigned short hu[4], lu[4];
#pragma unroll
    for (int i = 0; i < 4; ++i) {
        hu[i] = f2bf_rn(f[i]);
        float hf = __uint_as_float(((unsigned int)hu[i]) << 16);
        lu[i] = f2bf_rn(f[i] - hf);                    // residual, exact in fp32
    }
    hv.x = hu[0]; hv.y = hu[1]; hv.z = hu[2]; hv.w = hu[3];
    lv.x = lu[0]; lv.y = lu[1]; lv.z = lu[2]; lv.w = lu[3];
    *(ushort4*)&xhi[v] = hv;
    *(ushort4*)&xlo[v] = lv;
}

// ---------------------------------------------------------------------------
// Kernel 2: symmetric Gram tile (bf16-split MFMA) + count-sketch scatter.
// grid = 1088 blocks 1-D: batch = id & 7 (one batch per XCD -> 6.55 MB L2
// working set), pair = id >> 3 (row-major triangle).
// Scatter meta staged in LDS; bins updated with native ds_add_f32.
// ---------------------------------------------------------------------------
__device__ __forceinline__ void stage_tile(
    const unsigned short* __restrict__ src, size_t rowbase_elems,
    unsigned short* lds_tile, int wv, int lane, int k0)
{
#pragma unroll
    for (int half = 0; half < 2; ++half) {
        int ch  = wv * 2 + half;                       // 0..7 chunk of 8KB tile
        int row = ch * 16 + (lane >> 2);
        int kg  = (lane & 3) ^ ((lane >> 3) & 3);      // XOR swizzle (row>>1)&3
        const unsigned short* g = src + rowbase_elems
            + (size_t)row * KPAD + k0 + kg * 8;
        __builtin_amdgcn_global_load_lds(
            (__attribute__((address_space(1))) void*)g,
            (__attribute__((address_space(3))) void*)(lds_tile + ch * 512),
            16, 0, 0);
    }
}

__global__ __launch_bounds__(256, 2) void gram_scatter_kernel(
    const unsigned short* __restrict__ xhi,
    const unsigned short* __restrict__ xlo,
    const int*   __restrict__ h1, const float* __restrict__ s1,
    const int*   __restrict__ h2, const float* __restrict__ s2,
    float* __restrict__ part)
{
    __shared__ __align__(16) unsigned short smA_hi[128 * 32];
    __shared__ __align__(16) unsigned short smA_lo[128 * 32];
    __shared__ __align__(16) unsigned short smB_hi[128 * 32];
    __shared__ __align__(16) unsigned short smB_lo[128 * 32];
    __shared__ float bins[DDIM];                       // 32 KB private histogram
    __shared__ float4 metaA[128];                      // 2 KB scatter meta

    const int tid  = threadIdx.x;
    const int lane = tid & 63;
    const int wv   = tid >> 6;
    const int b    = blockIdx.x & 7;       // batch in low bits -> one batch/XCD
    const int pidx = blockIdx.x >> 3;      // triangular pair index

    // Triangular decode: pidx in [0,136) -> (tM, tN), tM <= tN, row-major
    int tM = 0, tN = 0;
    {
        int i = pidx;
#pragma unroll 1
        for (int t = 0; t < NTILE; ++t) {
            int cnt = NTILE - t;
            if (i < cnt) { tM = t; tN = t + i; break; }
            i -= cnt;
        }
    }
    const bool diag = (tM == tN);

    for (int i = tid; i < DDIM; i += 256) bins[i] = 0.0f;
    // (first __syncthreads inside k-loop orders this before any scatter)

    const int wrow = (wv >> 1) * 64;    // wave's 64x64 subtile origin
    const int wcol = (wv & 1) * 64;

    const size_t rowbaseA = ((size_t)b * CH + (size_t)tM * 128) * KPAD;
    const size_t rowbaseB = ((size_t)b * CH + (size_t)tN * 128) * KPAD;

    const unsigned short* fragBhi = diag ? smA_hi : smB_hi;
    const unsigned short* fragBlo = diag ? smA_lo : smB_lo;

    f32x4 acc[4][4];
    const f32x4 zv = {0.0f, 0.0f, 0.0f, 0.0f};
#pragma unroll
    for (int mi = 0; mi < 4; ++mi)
#pragma unroll
        for (int ni = 0; ni < 4; ++ni) acc[mi][ni] = zv;

    // fragment LDS offset: (row)*32 + fxor; XOR term is a per-lane constant
    const int fxor = (((lane >> 4) ^ ((lane >> 1) & 3)) << 3);
    const int rsel = lane & 15;

    for (int ks = 0; ks < KSTEPS; ++ks) {
        const int k0 = ks * 32;
        stage_tile(xhi, rowbaseA, smA_hi, wv, lane, k0);
        stage_tile(xlo, rowbaseA, smA_lo, wv, lane, k0);
        if (!diag) {
            stage_tile(xhi, rowbaseB, smB_hi, wv, lane, k0);
            stage_tile(xlo, rowbaseB, smB_lo, wv, lane, k0);
        }
        __syncthreads();

        bf16x8 ah[4], al[4], bh[4], bl[4];
#pragma unroll
        for (int i = 0; i < 4; ++i) {
            int offa = (wrow + i * 16 + rsel) * 32 + fxor;
            ah[i] = *(const bf16x8*)&smA_hi[offa];
            al[i] = *(const bf16x8*)&smA_lo[offa];
            int offb = (wcol + i * 16 + rsel) * 32 + fxor;
            bh[i] = *(const bf16x8*)&fragBhi[offb];
            bl[i] = *(const bf16x8*)&fragBlo[offb];
        }
#pragma unroll
        for (int mi = 0; mi < 4; ++mi)
#pragma unroll
            for (int ni = 0; ni < 4; ++ni) {
                acc[mi][ni] = __builtin_amdgcn_mfma_f32_16x16x32_bf16(ah[mi], bh[ni], acc[mi][ni], 0, 0, 0);
                acc[mi][ni] = __builtin_amdgcn_mfma_f32_16x16x32_bf16(ah[mi], bl[ni], acc[mi][ni], 0, 0, 0);
                acc[mi][ni] = __builtin_amdgcn_mfma_f32_16x16x32_bf16(al[mi], bh[ni], acc[mi][ni], 0, 0, 0);
            }
        __syncthreads();
    }

    // Stage scatter meta for this tile's 128 c1-rows into LDS.
    if (tid < 128) {
        int c1 = tM * 128 + tid;
        metaA[tid] = make_float4(s1[c1], __int_as_float(h1[c1]),
                                 s2[c1], __int_as_float(h2[c1]));
    }
    __syncthreads();

    // Scatter the 128x128 Gram tile into the LDS histogram.
    // C/D layout (m89-verified): col = lane&15, row = (lane>>4)*4 + reg
    // Off-diagonal pair: each entry contributes twice (G symmetric).
    const int c2b = tN * 128 + wcol + (lane & 15);
    const int rowsel = wrow + ((lane >> 4) << 2);
    int   h1c[4], h2c[4]; float s1c[4], s2c[4];
#pragma unroll
    for (int ni = 0; ni < 4; ++ni) {
        int c2 = c2b + ni * 16;
        h1c[ni] = h1[c2]; s1c[ni] = s1[c2];
        h2c[ni] = h2[c2]; s2c[ni] = s2[c2];
    }
#pragma unroll
    for (int mi = 0; mi < 4; ++mi) {
#pragma unroll
        for (int r = 0; r < 4; ++r) {
            float4 m = metaA[rowsel + mi * 16 + r];    // one ds_read_b128
            const float s1r = m.x, s2r = m.z;
            const int h1r = __float_as_int(m.y);
            const int h2r = __float_as_int(m.w);
#pragma unroll
            for (int ni = 0; ni < 4; ++ni) {
                float g = acc[mi][ni][r];
                FATOMIC(&bins[(h1r + h2c[ni]) & (DDIM - 1)], s1r * s2c[ni] * g);
                if (!diag)
                    FATOMIC(&bins[(h1c[ni] + h2r) & (DDIM - 1)], s1c[ni] * s2r * g);
            }
        }
    }

    __syncthreads();   // all scatters into bins complete

    // Flush to one of 17 part slots (8 blocks/slot), rotated start per block
    // to decontend cache lines.  Native global_atomic_add_f32.
    float* pb = part + ((size_t)((pidx % NSLOT) * BATCH + b) * DDIM);
    const int rot = (blockIdx.x & 31) << 8;
    for (int i = tid; i < DDIM; i += 256) {
        int j = (i + rot) & (DDIM - 1);
        FATOMIC(&pb[j], bins[j]);
    }
}

// ---------------------------------------------------------------------------
// Kernel 3: y[b,d] = sum over 17 part slots; accumulate norm[b] += sum|y|.
// grid 64: block j -> batch j>>3, d-slice (j&7)*1024.
// ---------------------------------------------------------------------------
__global__ __launch_bounds__(256) void reduce_kernel(
    const float* __restrict__ part, float* __restrict__ y,
    float* __restrict__ norm)
{
    const int tid = threadIdx.x;
    const int b  = blockIdx.x >> 3;
    const int d0 = (blockIdx.x & 7) * 1024;
    float ab = 0.0f;
    for (int dd = tid; dd < 1024; dd += 256) {
        int d = d0 + dd;
        float s = 0.0f;
#pragma unroll
        for (int p = 0; p < NSLOT; ++p)
            s += part[((size_t)p * BATCH + b) * DDIM + d];
        y[(size_t)b * DDIM + d] = s;
        ab += fabsf(s);   // sum|y| == sum feat_unnorm^2
    }
    __shared__ float red[256];
    red[tid] = ab;
    __syncthreads();
    for (int s = 128; s > 0; s >>= 1) {
        if (tid < s) red[tid] += red[tid + s];
        __syncthreads();
    }
    if (tid == 0) FATOMIC(&norm[b], red[0]);
}

// ---------------------------------------------------------------------------
// Kernel 4: fused signed-sqrt + L2-normalize + classifier GEMV.
// grid 64: block j owns d in [128j, 128j+128) for all batches.
// Writes feat to out and atomically accumulates bias-seeded logits.
// ---------------------------------------------------------------------------
__global__ __launch_bounds__(256) void logit_kernel(
    const float* __restrict__ y, const float* __restrict__ norm,
    const float* __restrict__ W, float* __restrict__ out)
{
    const int j = blockIdx.x;
    const int tid = threadIdx.x;
    __shared__ float fs[BATCH][128];                   // 4 KB
    for (int i = tid; i < BATCH * 128; i += 256) {
        int bb = i >> 7, dd = i & 127;
        float v = y[(size_t)bb * DDIM + j * 128 + dd];
        float inv = 1.0f / fmaxf(sqrtf(norm[bb]), 1e-12f);
        float f = copysignf(sqrtf(fabsf(v)), v) * inv;
        fs[bb][dd] = f;
        out[BATCH * NCLS + (size_t)bb * DDIM + j * 128 + dd] = f;
    }
    __syncthreads();
    if (tid < NCLS) {
        float a[BATCH];
#pragma unroll
        for (int bb = 0; bb < BATCH; ++bb) a[bb] = 0.0f;
        for (int dd = 0; dd < 128; ++dd) {
            float w = W[(size_t)(j * 128 + dd) * NCLS + tid];
#pragma unroll
            for (int bb = 0; bb < BATCH; ++bb) a[bb] += fs[bb][dd] * w;
        }
#pragma unroll
        for (int bb = 0; bb < BATCH; ++bb)
            FATOMIC(&out[bb * NCLS + tid], a[bb]);
    }
}

// ---------------------------------------------------------------------------
extern "C" void kernel_launch(void* const* d_in, const int* in_sizes, int n_in,
                              void* d_out, int out_size, void* d_ws, size_t ws_size,
                              hipStream_t stream)
{
    const float* x  = (const float*)d_in[0];
    const float* s1 = (const float*)d_in[1];
    const float* s2 = (const float*)d_in[2];
    const float* W  = (const float*)d_in[3];
    const float* bc = (const float*)d_in[4];
    const int*   h1 = (const int*)d_in[5];
    const int*   h2 = (const int*)d_in[6];
    float* out = (float*)d_out;

    // workspace layout: part (4.46MB) | y (256KB) | norm (256B) | xhi | xlo
    char* ws = (char*)d_ws;
    float* part = (float*)ws;
    const size_t partbytes = (size_t)NSLOT * BATCH * DDIM * sizeof(float);
    float* y    = (float*)(ws + partbytes);
    const size_t ybytes = (size_t)BATCH * DDIM * sizeof(float);
    float* norm = (float*)(ws + partbytes + ybytes);
    unsigned short* xhi = (unsigned short*)(ws + partbytes + ybytes + 256);
    unsigned short* xlo = xhi + (size_t)BATCH * CH * KPAD;

    split_kernel<<<(BATCH * CH * KPAD / 4 + 255) / 256, 256, 0, stream>>>(
        x, xhi, xlo, part, norm, bc, out);

    gram_scatter_kernel<<<NPAIR * BATCH, 256, 0, stream>>>(
        xhi, xlo, h1, s1, h2, s2, part);

    reduce_kernel<<<64, 256, 0, stream>>>(part, y, norm);

    logit_kernel<<<64, 256, 0, stream>>>(y, norm, W, out);
}